// Round 1
// baseline (271.099 us; speedup 1.0000x reference)
//
#include <hip/hip_runtime.h>
#include <hip/hip_bf16.h>
#include <math.h>

typedef __bf16 bf16x8 __attribute__((ext_vector_type(8)));
typedef float  f32x4  __attribute__((ext_vector_type(4)));

#define BS 4
#define CH 256
#define HW 4096
#define QB 64
#define KB 64
#define NKT (HW/KB)
#define LDK 264   // Ks row stride (elements), padded: 528B per row -> 2-way-free banks
#define LDP 80    // Ps row stride (elements), 160B per row, 16B-aligned

// ---------------- prep: build Kn[b][j][c], Qt[b][j][c], Kmt[b][c][j] (bf16) ----------------
// grid (HW/32, BS), block 256. LDS tile [256][33] f32 (pad 33 kills bank conflicts).
__global__ __launch_bounds__(256) void prep_kernel(
    const float* __restrict__ F, const float* __restrict__ mask,
    __bf16* __restrict__ Kn, __bf16* __restrict__ Qt, __bf16* __restrict__ Kmt)
{
  __shared__ float tile[256 * 33];
  __shared__ float red[256];    // [8 parts][32 jj]
  __shared__ float inv[32];
  __shared__ float mld[32];
  const int t  = threadIdx.x;
  const int b  = blockIdx.y;
  const int j0 = blockIdx.x * 32;

  // load F tile, coalesced: 8 c-rows x 32 jj per iteration
  {
    const int jj = t & 31, cr = t >> 5;
    for (int it = 0; it < 32; ++it) {
      int c = it * 8 + cr;
      tile[c * 33 + jj] = F[(size_t)(b * CH + c) * HW + j0 + jj];
    }
  }
  if (t < 32) mld[t] = mask[b * HW + j0 + t];
  __syncthreads();

  // row norms over channels (K = F^T + 1e-7)
  {
    const int jj = t & 31, part = t >> 5;
    float s = 0.f;
    for (int c = part * 32; c < part * 32 + 32; ++c) {
      float v = tile[c * 33 + jj] + 1e-7f;
      s += v * v;
    }
    red[part * 32 + jj] = s;
  }
  __syncthreads();
  if (t < 32) {
    float s = 0.f;
    for (int p = 0; p < 8; ++p) s += red[p * 32 + t];
    inv[t] = rsqrtf(s);
  }
  __syncthreads();

  // write Kn + Qt rows (coalesced over c), stash km in tile in-place
  for (int jj = 0; jj < 32; ++jj) {
    float v  = tile[t * 33 + jj];
    float kn = (v + 1e-7f) * inv[jj];
    size_t ro = (size_t)(b * HW + j0 + jj) * CH + t;
    Kn[ro] = (__bf16)kn;
    Qt[ro] = (__bf16)v;
    tile[t * 33 + jj] = kn * mld[jj];
  }
  __syncthreads();

  // write Kmt rows (coalesced over j)
  {
    const int jj = t & 31, cr = t >> 5;
    for (int it = 0; it < 32; ++it) {
      int c = it * 8 + cr;
      Kmt[(size_t)(b * CH + c) * HW + j0 + jj] = (__bf16)tile[c * 33 + jj];
    }
  }
}

// ---------------- skip flags ----------------
__global__ __launch_bounds__(256) void skip_kernel(
    const float* __restrict__ mask, float* __restrict__ flags)
{
  __shared__ float wsum[4];
  const int b = blockIdx.x, t = threadIdx.x;
  float s = 0.f;
  for (int i = t; i < HW; i += 256) s += mask[b * HW + i];
  for (int off = 32; off; off >>= 1) s += __shfl_down(s, off);
  if ((t & 63) == 0) wsum[t >> 6] = s;
  __syncthreads();
  if (t == 0) {
    float tot = wsum[0] + wsum[1] + wsum[2] + wsum[3];
    flags[b] = (tot > (float)(HW - 10)) ? 1.f : 0.f;
  }
}

// ---------------- flash attention ----------------
// grid 256 blocks (xcd-swizzled -> (b, qtile)), block 256 = 4 waves.
// Wave w: owns q-rows [16w,16w+16) for S^T + softmax; owns channel slab [64w,64w+64) for PV.
__global__ __launch_bounds__(256) void attn_kernel(
    const __bf16* __restrict__ Kn, const __bf16* __restrict__ Qt,
    const __bf16* __restrict__ Kmt, const float* __restrict__ F,
    const float* __restrict__ mask, const float* __restrict__ flags,
    float* __restrict__ out)
{
  __shared__ __bf16 Ks[64 * LDK];
  __shared__ __bf16 Ps[64 * LDP];
  __shared__ float alpha_s[64];
  __shared__ float l_s[64];

  const int t = threadIdx.x;
  const int w = t >> 6, lane = t & 63, lg = lane >> 4, lr = lane & 15;

  // XCD-aware swizzle: batch b -> XCDs {2b, 2b+1}; bijective remap of 256 block ids.
  const int bid  = blockIdx.y * gridDim.x + blockIdx.x;
  const int xcd  = bid & 7, slot = bid >> 3;
  const int b    = xcd >> 1;
  const int q0   = ((xcd & 1) * 32 + slot) * QB;

  // Q fragments for this wave's 16 q-rows, held in registers (A-operand of S^T)
  bf16x8 aq[8];
  {
    const __bf16* qrow = Qt + (size_t)(b * HW + q0 + 16 * w + lr) * CH;
    #pragma unroll
    for (int ks = 0; ks < 8; ++ks)
      aq[ks] = *(const bf16x8*)(qrow + ks * 32 + lg * 8);
  }

  f32x4 acc[4][4];
  #pragma unroll
  for (int i = 0; i < 4; ++i)
    #pragma unroll
    for (int j = 0; j < 4; ++j) acc[i][j] = (f32x4)0.f;
  float m_run[4], l_run[4];
  #pragma unroll
  for (int r = 0; r < 4; ++r) { m_run[r] = -1e30f; l_run[r] = 0.f; }

  for (int kt = 0; kt < NKT; ++kt) {
    // stage Kn tile [64 j][256 c] -> Ks (coalesced 16B loads)
    {
      const int cb = (t & 31) * 8;
      const int rb = t >> 5;
      #pragma unroll
      for (int it = 0; it < 8; ++it) {
        int r = it * 8 + rb;
        uint4 v = *(const uint4*)(Kn + (size_t)(b * HW + kt * KB + r) * CH + cb);
        *(uint4*)(Ks + r * LDK + cb) = v;
      }
    }
    __syncthreads();

    // S^T tile: rows = wave's 16 q, cols = 64 j
    f32x4 s_acc[4];
    #pragma unroll
    for (int nt = 0; nt < 4; ++nt) s_acc[nt] = (f32x4)0.f;
    #pragma unroll
    for (int ks = 0; ks < 8; ++ks) {
      bf16x8 a = aq[ks];
      #pragma unroll
      for (int nt = 0; nt < 4; ++nt) {
        bf16x8 bb = *(const bf16x8*)(Ks + (nt * 16 + lr) * LDK + ks * 32 + lg * 8);
        s_acc[nt] = __builtin_amdgcn_mfma_f32_16x16x32_bf16(a, bb, s_acc[nt], 0, 0, 0);
      }
    }

    // online softmax over this tile's 64 j, per q-row (row = lg*4 + r; 16 lanes share a row)
    float a_r[4];
    #pragma unroll
    for (int r = 0; r < 4; ++r) {
      float tm = fmaxf(fmaxf(s_acc[0][r], s_acc[1][r]), fmaxf(s_acc[2][r], s_acc[3][r]));
      #pragma unroll
      for (int off = 8; off; off >>= 1) tm = fmaxf(tm, __shfl_xor(tm, off));
      float mn = fmaxf(m_run[r], tm);
      a_r[r] = __expf(m_run[r] - mn);
      m_run[r] = mn;
      float ps = 0.f;
      #pragma unroll
      for (int nt = 0; nt < 4; ++nt) {
        float e = __expf(s_acc[nt][r] - mn);
        s_acc[nt][r] = e;          // reuse as P
        ps += e;
      }
      #pragma unroll
      for (int off = 8; off; off >>= 1) ps += __shfl_xor(ps, off);
      l_run[r] = l_run[r] * a_r[r] + ps;
    }
    if (lr == 0) {
      #pragma unroll
      for (int r = 0; r < 4; ++r) alpha_s[16 * w + lg * 4 + r] = a_r[r];
    }
    #pragma unroll
    for (int nt = 0; nt < 4; ++nt)
      #pragma unroll
      for (int r = 0; r < 4; ++r)
        Ps[(16 * w + lg * 4 + r) * LDP + nt * 16 + lr] = (__bf16)s_acc[nt][r];
    __syncthreads();

    // rescale O by alpha[q], then O += Kmt_tile * P
    #pragma unroll
    for (int nt = 0; nt < 4; ++nt) {
      float al = alpha_s[nt * 16 + lr];
      #pragma unroll
      for (int mt = 0; mt < 4; ++mt) acc[mt][nt] *= al;
    }
    #pragma unroll
    for (int ks = 0; ks < 2; ++ks) {
      bf16x8 bfr[4];
      #pragma unroll
      for (int nt = 0; nt < 4; ++nt)
        bfr[nt] = *(const bf16x8*)(Ps + (nt * 16 + lr) * LDP + ks * 32 + lg * 8);
      #pragma unroll
      for (int mt = 0; mt < 4; ++mt) {
        int c = 64 * w + mt * 16 + lr;
        bf16x8 afr = *(const bf16x8*)(Kmt + (size_t)(b * CH + c) * HW + kt * KB + ks * 32 + lg * 8);
        #pragma unroll
        for (int nt = 0; nt < 4; ++nt)
          acc[mt][nt] = __builtin_amdgcn_mfma_f32_16x16x32_bf16(afr, bfr[nt], acc[mt][nt], 0, 0, 0);
      }
    }
    __syncthreads();   // Ks/Ps safe to overwrite next iteration after this point
  }

  // epilogue: normalize by l, blend with foreground, skip override
  if (lr == 0) {
    #pragma unroll
    for (int r = 0; r < 4; ++r) l_s[16 * w + lg * 4 + r] = l_run[r];
  }
  __syncthreads();
  const bool skip = flags[b] > 0.5f;
  #pragma unroll
  for (int nt = 0; nt < 4; ++nt) {
    int q = nt * 16 + lr;
    float linv = 1.f / l_s[q];
    float mv = mask[b * HW + q0 + q];
    float w1 = 1.f - mv;
    #pragma unroll
    for (int mt = 0; mt < 4; ++mt) {
      #pragma unroll
      for (int r = 0; r < 4; ++r) {
        int c = 64 * w + mt * 16 + lg * 4 + r;
        size_t idx = (size_t)(b * CH + c) * HW + q0 + q;
        float f = F[idx];
        float o = acc[mt][nt][r] * linv;
        out[idx] = skip ? f : (o * w1 + f * mv);
      }
    }
  }
}

extern "C" void kernel_launch(void* const* d_in, const int* in_sizes, int n_in,
                              void* d_out, int out_size, void* d_ws, size_t ws_size,
                              hipStream_t stream) {
  const float* F    = (const float*)d_in[0];
  const float* mask = (const float*)d_in[1];
  float* out = (float*)d_out;

  __bf16* Kn  = (__bf16*)d_ws;
  __bf16* Qt  = Kn  + (size_t)BS * HW * CH;
  __bf16* Kmt = Qt  + (size_t)BS * HW * CH;
  float*  flags = (float*)(Kmt + (size_t)BS * HW * CH);

  prep_kernel<<<dim3(HW / 32, BS), 256, 0, stream>>>(F, mask, Kn, Qt, Kmt);
  skip_kernel<<<BS, 256, 0, stream>>>(mask, flags);
  attn_kernel<<<dim3(64, BS), 256, 0, stream>>>(Kn, Qt, Kmt, F, mask, flags, out);
}